// Round 1
// baseline (76.734 us; speedup 1.0000x reference)
//
#include <hip/hip_runtime.h>
#include <stdint.h>

// Problem constants (match reference):
#define BB   256      // batch
#define LL   2048     // sequence length
#define DD   128      // embedding dim
#define TMAX 48       // time bins
#define BLOCK 1024    // 16 waves (gather kernel)
#define NWAVE (BLOCK / 64)
#define UN   4        // wave-loads per iter; 4 tokens each -> 16 tokens/iter
#define PADQ 16       // bins padded to multiple of 16 tokens

#define SORT_N      (LL + PADQ * TMAX)   // 2816 ints of sorted row offsets
#define SORT_STRIDE 3072                 // ints per batch in ws (sorted + start + cnt, padded)
#define CONVBLKS    750                  // V*D/4 float4 / 256 threads

// R1: shared-float atomicAdd = CAS loop (345us) -> counting-sort + register acc.
// R3: float4 half-wave gathers: kernel ~19us (dur_us - ~56us harness fills).
// R4/R5: deeper ILP + 2-block overlap neutral -> not latency- or overlap-bound.
// R6: bf16 table (256B rows, quarter-wave gathers): kernel ~17.5us.
// R7: PRE-SCALED table srow[id] = bf16(exp(embW[id]) * embX[id]).
// R8: split-pipeline: kernel A = convert (750 blks) + parse/sort (256 blks)
//     overlapped; sorted offsets spilled to ws. Kernel B = gather only.
//     Moves the serial phase-1 (~2-2.5us) off the critical path; gather is
//     at its L2-BW roofline (~3.8us/block-wave) so this targets the rest.

// ---------------- kernel A: table convert + per-batch counting sort ----------
__global__ __launch_bounds__(256) void prep_kernel(
    const float* __restrict__ X,        // [B][L][2]
    const float* __restrict__ embX,     // [V][D] fp32
    const float* __restrict__ embW,     // [V+1] fp32
    uint16_t* __restrict__ ebf,         // [V][D] bf16 pre-scaled out
    int* __restrict__ gsort)            // [B][SORT_STRIDE] sorted offsets out
{
    const int blk = blockIdx.x;
    const int tid = threadIdx.x;

    if (blk < CONVBLKS) {
        // ---- table conversion: V*D = 192000 float4, exact cover ----
        int i  = blk * 256 + tid;
        int id = i >> 5;                       // 32 float4 per 128-col row
        float w = __expf(embW[id]);            // broadcast load, L1-resident
        float4 v = ((const float4*)embX)[i];
        uint32_t u0 = __float_as_uint(v.x * w), u1 = __float_as_uint(v.y * w),
                 u2 = __float_as_uint(v.z * w), u3 = __float_as_uint(v.w * w);
        // RTNE fp32 -> bf16 (no NaN/Inf present)
        u0 += 0x7fffu + ((u0 >> 16) & 1u);
        u1 += 0x7fffu + ((u1 >> 16) & 1u);
        u2 += 0x7fffu + ((u2 >> 16) & 1u);
        u3 += 0x7fffu + ((u3 >> 16) & 1u);
        ushort4 o = { (uint16_t)(u0 >> 16), (uint16_t)(u1 >> 16),
                      (uint16_t)(u2 >> 16), (uint16_t)(u3 >> 16) };
        ((ushort4*)ebf)[i] = o;
        return;
    }

    // ---- parse + histogram + scan + counting sort for one batch ----
    __shared__ int s_sorted[SORT_N];
    __shared__ int s_cnt[TMAX];
    __shared__ int s_start[TMAX];
    __shared__ int s_ofs[TMAX];

    const int b    = blk - CONVBLKS;
    const int lane = tid & 63;
    const int wv   = tid >> 6;

    if (tid < TMAX) s_cnt[tid] = 0;
    __syncthreads();

    const float2* Xb = (const float2*)(X + (size_t)b * LL * 2);
    int tok_off[8];   // 2048 tokens / 256 threads = 8 per thread
    int tok_bin[8];
    #pragma unroll
    for (int j = 0; j < 8; ++j) {
        float2 x = Xb[tid + j * 256];     // coalesced 8B loads
        int id  = (int)x.y;               // ids in [1, V), exact in fp32
        int bin = (int)x.x;               // T >= 0, trunc == floor
        bin = bin < 0 ? 0 : (bin > TMAX - 1 ? TMAX - 1 : bin);
        tok_off[j] = id << 8;             // id * DD * 2 bytes
        tok_bin[j] = bin;
        atomicAdd(&s_cnt[bin], 1);        // native ds_add_u32
    }
    __syncthreads();

    // exclusive scan over 48 bins, each padded to x16 (wave 0)
    if (wv == 0) {
        int raw = (lane < TMAX) ? s_cnt[lane] : 0;
        int pad = (raw + PADQ - 1) & ~(PADQ - 1);
        int c = pad;
        #pragma unroll
        for (int d = 1; d < 64; d <<= 1) {
            int t = __shfl_up(c, d);
            if (lane >= d) c += t;
        }
        if (lane < TMAX) { s_start[lane] = c - pad; s_ofs[lane] = c - pad; }
    }
    __syncthreads();

    // sentinel fill (row 0 is all-zero after scaling) + scatter
    if (tid < TMAX * PADQ / 4) {          // 192 threads, 4 slots each
        #pragma unroll
        for (int q = 0; q < 4; ++q) {
            int s   = tid * 4 + q;
            int t   = s >> 4;             // bin
            int j   = s & (PADQ - 1);
            int raw = s_cnt[t];
            int p   = ((raw + PADQ - 1) & ~(PADQ - 1)) - raw;
            if (j < p) s_sorted[s_start[t] + raw + j] = 0;
        }
    }
    #pragma unroll
    for (int j = 0; j < 8; ++j) {
        int pos = atomicAdd(&s_ofs[tok_bin[j]], 1);   // ds_add_rtn_u32
        s_sorted[pos] = tok_off[j];                   // scattered ds_write_b32
    }
    __syncthreads();

    // spill sorted offsets + bin metadata to workspace (coalesced)
    int* gb = gsort + (size_t)b * SORT_STRIDE;
    for (int i = tid; i < SORT_N; i += 256) gb[i] = s_sorted[i];
    if (tid < TMAX) {
        gb[SORT_N + tid]        = s_start[tid];
        gb[SORT_N + TMAX + tid] = s_cnt[tid];
    }
}

// ---------------- kernel B: gather + mean, straight to the roofline ---------
__global__ __launch_bounds__(BLOCK, 1) void gather_kernel(
    const uint16_t* __restrict__ ebf,   // [V][D] bf16 pre-scaled, row = 256B
    const int* __restrict__ gsort,      // [B][SORT_STRIDE]
    float* __restrict__ out)            // [B][TMAX][D]
{
    __shared__ int s_sorted[SORT_N];
    __shared__ int s_start[TMAX];
    __shared__ int s_cnt[TMAX];

    const int b    = blockIdx.x;
    const int tid  = threadIdx.x;
    const int lane = tid & 63;
    const int wv   = tid >> 6;

    const int* gb = gsort + (size_t)b * SORT_STRIDE;
    for (int i = tid; i < SORT_N; i += BLOCK) s_sorted[i] = gb[i];
    if (tid < TMAX)                        s_start[tid]      = gb[SORT_N + tid];
    else if (tid >= 64 && tid < 64 + TMAX) s_cnt[tid - 64]   = gb[SORT_N + TMAX + tid - 64];
    __syncthreads();

    // quarter-wave bf16 row gathers: 1 wave-load = 4 tokens
    const char* base  = (const char*)ebf;
    const int   sub   = lane >> 4;                // token slot 0..3
    const int   laneq = lane & 15;                // columns [laneq*8, laneq*8+8)
    const int   loff  = laneq << 4;               // 16B per lane within row
    for (int t = wv; t < TMAX; t += NWAVE) {      // 3 bins per wave
        const int start = s_start[t];
        const int n     = s_cnt[t];
        const int npad  = (n + PADQ - 1) & ~(PADQ - 1);
        float acc[8];
        #pragma unroll
        for (int c = 0; c < 8; ++c) acc[c] = 0.0f;

        for (int i = 0; i < npad; i += 4 * UN) {  // 16 tokens (4 wave-loads)/iter
            uint4 r[UN];
            #pragma unroll
            for (int j = 0; j < UN; ++j) {
                int off = s_sorted[start + i + 4 * j + sub];  // b32 broadcast read
                r[j] = *(const uint4*)(base + off + loff);
            }
            #pragma unroll
            for (int j = 0; j < UN; ++j) {
                const uint32_t* ru = (const uint32_t*)&r[j];
                #pragma unroll
                for (int k = 0; k < 4; ++k) {
                    uint32_t u = ru[k];
                    acc[2 * k]     += __uint_as_float(u << 16);          // even col
                    acc[2 * k + 1] += __uint_as_float(u & 0xffff0000u);  // odd col
                }
            }
        }
        // combine the 4 token-slots (same columns, different tokens)
        #pragma unroll
        for (int c = 0; c < 8; ++c) {
            acc[c] += __shfl_xor(acc[c], 16);
            acc[c] += __shfl_xor(acc[c], 32);
        }
        if (sub == 0) {
            float inv = 1.0f / ((float)n + 1e-6f);
            float4 v0 = { acc[0] * inv, acc[1] * inv, acc[2] * inv, acc[3] * inv };
            float4 v1 = { acc[4] * inv, acc[5] * inv, acc[6] * inv, acc[7] * inv };
            float* op = out + (size_t)b * TMAX * DD + t * DD + laneq * 8;
            *(float4*)op       = v0;
            *(float4*)(op + 4) = v1;
        }
    }
}

extern "C" void kernel_launch(void* const* d_in, const int* in_sizes, int n_in,
                              void* d_out, int out_size, void* d_ws, size_t ws_size,
                              hipStream_t stream) {
    const float* X    = (const float*)d_in[0];   // B*L*2 fp32
    const float* embX = (const float*)d_in[1];   // V*D fp32
    const float* embW = (const float*)d_in[2];   // (V+1) fp32
    float* out        = (float*)d_out;           // B*TMAX*D fp32

    // ws layout: [0, 1.5MiB) bf16 table; [1.5MiB, +3MiB) sorted offsets
    uint16_t* ebf = (uint16_t*)d_ws;                         // V*D bf16 (1,536,000 B)
    int* gsort    = (int*)((char*)d_ws + (1 << 20) + (1 << 19));  // 1.5 MiB offset

    prep_kernel  <<<dim3(CONVBLKS + BB), dim3(256),  0, stream>>>(X, embX, embW, ebf, gsort);
    gather_kernel<<<dim3(BB),            dim3(BLOCK), 0, stream>>>(ebf, gsort, out);
}